// Round 1
// baseline (1969.131 us; speedup 1.0000x reference)
//
#include <hip/hip_runtime.h>
#include <stdint.h>

#define N_SITES 144
#define NHID    256
#define NSAMP   1024
#define MB      4          // samples per block
#define TPB     256
#define PARTITIONABLE 1    // modern JAX default (>=0.4.30). Set 0 for legacy threefry pairing.

__device__ __forceinline__ uint32_t rotl32(uint32_t v, uint32_t r) {
    return (v << r) | (v >> (32u - r));
}

// JAX threefry2x32: 20 rounds, key injections every 4
__device__ __forceinline__ void threefry(uint32_t k0, uint32_t k1,
                                         uint32_t x0, uint32_t x1,
                                         uint32_t& o0, uint32_t& o1) {
    uint32_t ks0 = k0, ks1 = k1, ks2 = k0 ^ k1 ^ 0x1BD11BDAu;
    x0 += ks0; x1 += ks1;
#define RG4(a,b,c,d) \
    x0 += x1; x1 = rotl32(x1,a); x1 ^= x0; \
    x0 += x1; x1 = rotl32(x1,b); x1 ^= x0; \
    x0 += x1; x1 = rotl32(x1,c); x1 ^= x0; \
    x0 += x1; x1 = rotl32(x1,d); x1 ^= x0;
    RG4(13,15,26,6)  x0 += ks1; x1 += ks2 + 1u;
    RG4(17,29,16,24) x0 += ks2; x1 += ks0 + 2u;
    RG4(13,15,26,6)  x0 += ks0; x1 += ks1 + 3u;
    RG4(17,29,16,24) x0 += ks1; x1 += ks2 + 4u;
    RG4(13,15,26,6)  x0 += ks2; x1 += ks0 + 5u;
#undef RG4
    o0 = x0; o1 = x1;
}

// legacy (non-partitionable) random_bits element f of an even-size draw
__device__ __forceinline__ uint32_t rbits_orig(uint32_t ka, uint32_t kb,
                                               uint32_t f, uint32_t half) {
    uint32_t o0, o1;
    if (f < half) { threefry(ka, kb, f, f + half, o0, o1); return o0; }
    threefry(ka, kb, f - half, f, o0, o1); return o1;
}

__device__ __forceinline__ float gumbel_from_bits(uint32_t bits) {
#pragma clang fp contract(off)
    const float TINY = 1.17549435e-38f;          // finfo(f32).tiny
    uint32_t fb = (bits >> 9) | 0x3f800000u;
    float u = __uint_as_float(fb) - 1.0f;        // [0,1)
    u = u * (1.0f - TINY) + TINY;                // matches JAX uniform()
    u = fmaxf(TINY, u);
    return -logf(-logf(u));
}

__global__ __launch_bounds__(TPB, 1)
void rnn_sample_kernel(const float* __restrict__ kern,   // [2,768]
                       const float* __restrict__ rec,    // [256,768]
                       const float* __restrict__ bias,   // [2,768]
                       const float* __restrict__ dw,     // [256,2]
                       const float* __restrict__ db,     // [2]
                       float* __restrict__ out)          // samples[1024*144] ++ logP[1024]
{
    const int t   = threadIdx.x;
    const int blk = blockIdx.x;
    const int b0  = blk * MB;
    const int wv  = t >> 6;
    const int lane = t & 63;

    __shared__ float4   hs4[NHID];          // h[k] packed over 4 samples
    __shared__ uint32_t keyA[N_SITES], keyB[N_SITES];
    __shared__ float    wred[4][8];         // per-wave dense partials
    __shared__ float    logitsS[MB][2];
    __shared__ float    gumS[MB][2];
    __shared__ int      sPrev[MB];
    __shared__ float    lgP[MB];

    // per-thread column set: {t, t+256, t+512} = (z, r, n) gate columns
    const int c0 = t, c1 = t + 256, c2 = t + 512;
    const float kz0 = kern[c0],       kr0 = kern[c1],       kn0 = kern[c2];
    const float kz1 = kern[768 + c0], kr1 = kern[768 + c1], kn1 = kern[768 + c2];
    const float b0z = bias[c0],       b0r = bias[c1],       b0n = bias[c2];
    const float b1z = bias[768 + c0], b1r = bias[768 + c1], b1n = bias[768 + c2];
    const float dwa = dw[2 * t], dwb = dw[2 * t + 1];
    const float dba = db[0],     dbb = db[1];

    hs4[t] = make_float4(0.f, 0.f, 0.f, 0.f);
    if (t < MB) { sPrev[t] = -1; lgP[t] = 0.f; }
    if (t < N_SITES) {
#if PARTITIONABLE
        uint32_t o0, o1;
        threefry(0u, 42u, 0u, (uint32_t)t, o0, o1);   // foldlike split: counter = n
        keyA[t] = o0; keyB[t] = o1;
#else
        keyA[t] = rbits_orig(0u, 42u, 2u * (uint32_t)t,      N_SITES);
        keyB[t] = rbits_orig(0u, 42u, 2u * (uint32_t)t + 1u, N_SITES);
#endif
    }
    __syncthreads();

    for (int n = 0; n < N_SITES; ++n) {
        // ---- phase A: gh = h @ rec_kernel (pure dot; bias added later) ----
        float acc[MB][3];
#pragma unroll
        for (int m = 0; m < MB; ++m) { acc[m][0] = 0.f; acc[m][1] = 0.f; acc[m][2] = 0.f; }

        const float* rp = rec + t;
#pragma unroll 8
        for (int k = 0; k < NHID; ++k) {
            float4 h4 = hs4[k];                 // broadcast ds_read_b128
            float w0 = rp[0], w1 = rp[256], w2 = rp[512];
            rp += 768;
            acc[0][0] = fmaf(h4.x, w0, acc[0][0]);
            acc[1][0] = fmaf(h4.y, w0, acc[1][0]);
            acc[2][0] = fmaf(h4.z, w0, acc[2][0]);
            acc[3][0] = fmaf(h4.w, w0, acc[3][0]);
            acc[0][1] = fmaf(h4.x, w1, acc[0][1]);
            acc[1][1] = fmaf(h4.y, w1, acc[1][1]);
            acc[2][1] = fmaf(h4.z, w1, acc[2][1]);
            acc[3][1] = fmaf(h4.w, w1, acc[3][1]);
            acc[0][2] = fmaf(h4.x, w2, acc[0][2]);
            acc[1][2] = fmaf(h4.y, w2, acc[1][2]);
            acc[2][2] = fmaf(h4.z, w2, acc[2][2]);
            acc[3][2] = fmaf(h4.w, w2, acc[3][2]);
        }
        __syncthreads();   // B1: all phase-A reads of hs4 complete

        // ---- phase B: gates + h update (one hidden unit per thread, 4 samples) ----
        float4 ho = hs4[t];
        float hold[MB] = { ho.x, ho.y, ho.z, ho.w };
        float hnew[MB];
        {
#pragma clang fp contract(off)
#pragma unroll
            for (int m = 0; m < MB; ++m) {
                const int sp = sPrev[m];
                float xz = (sp == 0) ? kz0 : ((sp == 1) ? kz1 : 0.f);
                float xr = (sp == 0) ? kr0 : ((sp == 1) ? kr1 : 0.f);
                float xh = (sp == 0) ? kn0 : ((sp == 1) ? kn1 : 0.f);
                xz = xz + b0z;  xr = xr + b0r;  xh = xh + b0n;
                const float hz = acc[m][0] + b1z;
                const float hr = acc[m][1] + b1r;
                const float hn = acc[m][2] + b1n;
                const float z = 1.0f / (1.0f + expf(-(xz + hz)));
                const float r = 1.0f / (1.0f + expf(-(xr + hr)));
                const float rhn = r * hn;
                const float hh = tanhf(xh + rhn);
                hnew[m] = z * hold[m] + (1.0f - z) * hh;
            }
        }
        hs4[t] = make_float4(hnew[0], hnew[1], hnew[2], hnew[3]);

        // ---- phase C: dense logits partial reduction (h @ dense_w) ----
#pragma unroll
        for (int m = 0; m < MB; ++m) {
            float va = hnew[m] * dwa;
            float vb = hnew[m] * dwb;
#pragma unroll
            for (int off = 32; off > 0; off >>= 1) {
                va += __shfl_xor(va, off, 64);
                vb += __shfl_xor(vb, off, 64);
            }
            if (lane == 0) { wred[wv][2 * m] = va; wred[wv][2 * m + 1] = vb; }
        }
        __syncthreads();   // B2

        // ---- phase D1: logits + gumbel (8 threads) ----
        if (t < 2 * MB) {
            const int m = t >> 1, kk = t & 1;
            float s = wred[0][t] + wred[1][t] + wred[2][t] + wred[3][t];
            logitsS[m][kk] = s + ((kk == 0) ? dba : dbb);
            const uint32_t f = 2u * (uint32_t)(b0 + m) + (uint32_t)kk;
            uint32_t bits;
#if PARTITIONABLE
            uint32_t o0, o1;
            threefry(keyA[n], keyB[n], 0u, f, o0, o1);
            bits = o0 ^ o1;                      // 32-bit fold
#else
            bits = rbits_orig(keyA[n], keyB[n], f, NSAMP);
#endif
            gumS[m][kk] = gumbel_from_bits(bits);
        }
        __syncthreads();   // B3

        // ---- phase D2: softmax + categorical + logP (4 threads) ----
        if (t < MB) {
#pragma clang fp contract(off)
            const int m = t;
            const float l0 = logitsS[m][0], l1 = logitsS[m][1];
            const float mx = fmaxf(l0, l1);
            const float e0 = expf(l0 - mx), e1 = expf(l1 - mx);
            const float den = e0 + e1;
            const float lp0 = logf(1e-10f + e0 / den);
            const float lp1 = logf(1e-10f + e1 / den);
            const float v0 = gumS[m][0] + lp0;
            const float v1 = gumS[m][1] + lp1;
            const int s = (v1 > v0) ? 1 : 0;     // argmax, first-index tie-break
            sPrev[m] = s;
            lgP[m] = lgP[m] + (s ? lp1 : lp0);
            out[(size_t)(b0 + m) * N_SITES + n] = (float)s;
        }
        __syncthreads();   // B4: sPrev/hs4 stable for next step
    }

    if (t < MB) out[(size_t)NSAMP * N_SITES + (b0 + t)] = lgP[t];
}

extern "C" void kernel_launch(void* const* d_in, const int* in_sizes, int n_in,
                              void* d_out, int out_size, void* d_ws, size_t ws_size,
                              hipStream_t stream) {
    (void)in_sizes; (void)n_in; (void)d_ws; (void)ws_size; (void)out_size;
    const float* kern = (const float*)d_in[0];
    const float* rec  = (const float*)d_in[1];
    const float* bias = (const float*)d_in[2];
    const float* dwp  = (const float*)d_in[3];
    const float* dbp  = (const float*)d_in[4];
    float* out = (float*)d_out;
    rnn_sample_kernel<<<NSAMP / MB, TPB, 0, stream>>>(kern, rec, bias, dwp, dbp, out);
}

// Round 2
// 1560.725 us; speedup vs baseline: 1.2617x; 1.2617x over previous
//
#include <hip/hip_runtime.h>
#include <stdint.h>

#define N_SITES 144
#define NHID    256
#define NSAMP   1024
#define MB      4          // samples per block
#define TPB     768        // one gate-column per thread; 12 waves = 3 waves/SIMD
#define PARTITIONABLE 1

__device__ __forceinline__ uint32_t rotl32(uint32_t v, uint32_t r) {
    return (v << r) | (v >> (32u - r));
}

// JAX threefry2x32: 20 rounds, key injections every 4
__device__ __forceinline__ void threefry(uint32_t k0, uint32_t k1,
                                         uint32_t x0, uint32_t x1,
                                         uint32_t& o0, uint32_t& o1) {
    uint32_t ks0 = k0, ks1 = k1, ks2 = k0 ^ k1 ^ 0x1BD11BDAu;
    x0 += ks0; x1 += ks1;
#define RG4(a,b,c,d) \
    x0 += x1; x1 = rotl32(x1,a); x1 ^= x0; \
    x0 += x1; x1 = rotl32(x1,b); x1 ^= x0; \
    x0 += x1; x1 = rotl32(x1,c); x1 ^= x0; \
    x0 += x1; x1 = rotl32(x1,d); x1 ^= x0;
    RG4(13,15,26,6)  x0 += ks1; x1 += ks2 + 1u;
    RG4(17,29,16,24) x0 += ks2; x1 += ks0 + 2u;
    RG4(13,15,26,6)  x0 += ks0; x1 += ks1 + 3u;
    RG4(17,29,16,24) x0 += ks1; x1 += ks2 + 4u;
    RG4(13,15,26,6)  x0 += ks2; x1 += ks0 + 5u;
#undef RG4
    o0 = x0; o1 = x1;
}

__device__ __forceinline__ float gumbel_from_bits(uint32_t bits) {
#pragma clang fp contract(off)
    const float TINY = 1.17549435e-38f;          // finfo(f32).tiny
    uint32_t fb = (bits >> 9) | 0x3f800000u;
    float u = __uint_as_float(fb) - 1.0f;        // [0,1)
    u = u * (1.0f - TINY) + TINY;                // matches JAX uniform()
    u = fmaxf(TINY, u);
    return -logf(-logf(u));
}

__global__ __launch_bounds__(TPB, 1)
void rnn_sample_kernel(const float* __restrict__ kern,   // [2,768]
                       const float* __restrict__ rec,    // [256,768]
                       const float* __restrict__ bias,   // [2,768]
                       const float* __restrict__ dw,     // [256,2]
                       const float* __restrict__ db,     // [2]
                       float* __restrict__ out)          // samples[1024*144] ++ logP[1024]
{
    const int t    = threadIdx.x;          // 0..767 == gate column index
    const int blk  = blockIdx.x;
    const int b0   = blk * MB;
    const int wv   = t >> 6;               // wave id (phase C uses 0..3)
    const int lane = t & 63;

    __shared__ float4   hs4[NHID];          // h[k] packed over 4 samples (4 KB)
    __shared__ float    pacc[MB][TPB];      // phase-A partials, [sample][col] (12 KB)
    __shared__ uint32_t keyA[N_SITES], keyB[N_SITES];
    __shared__ float    wred[4][8];         // per-wave dense partials (waves 0..3)
    __shared__ int      sPrev[MB];
    __shared__ float    lgP[MB];

    // ---- per-thread constants (threads 0..255 only: gate triples) ----
    float kz0 = 0.f, kr0 = 0.f, kn0 = 0.f, kz1 = 0.f, kr1 = 0.f, kn1 = 0.f;
    float b0z = 0.f, b0r = 0.f, b0n = 0.f, b1z = 0.f, b1r = 0.f, b1n = 0.f;
    float dwa = 0.f, dwb = 0.f, dba = 0.f, dbb = 0.f;
    if (t < NHID) {
        const int c0 = t, c1 = t + 256, c2 = t + 512;
        kz0 = kern[c0];       kr0 = kern[c1];       kn0 = kern[c2];
        kz1 = kern[768 + c0]; kr1 = kern[768 + c1]; kn1 = kern[768 + c2];
        b0z = bias[c0];       b0r = bias[c1];       b0n = bias[c2];
        b1z = bias[768 + c0]; b1r = bias[768 + c1]; b1n = bias[768 + c2];
        dwa = dw[2 * t];      dwb = dw[2 * t + 1];
        dba = db[0];          dbb = db[1];
        hs4[t] = make_float4(0.f, 0.f, 0.f, 0.f);
    }
    if (t < MB) { sPrev[t] = -1; lgP[t] = 0.f; }
    if (t < N_SITES) {
        uint32_t o0, o1;
        threefry(0u, 42u, 0u, (uint32_t)t, o0, o1);   // foldlike split: counter = n
        keyA[t] = o0; keyB[t] = o1;
    }
    __syncthreads();

    for (int n = 0; n < N_SITES; ++n) {
        // ---- phase A: one column per thread, full k chain (bit-identical order) ----
        float a0 = 0.f, a1 = 0.f, a2 = 0.f, a3 = 0.f;
        {
            const float* rp = rec + t;
#pragma unroll 8
            for (int k = 0; k < NHID; ++k) {
                float4 h4 = hs4[k];          // broadcast ds_read_b128
                float w  = rp[0];
                rp += 768;
                a0 = fmaf(h4.x, w, a0);
                a1 = fmaf(h4.y, w, a1);
                a2 = fmaf(h4.z, w, a2);
                a3 = fmaf(h4.w, w, a3);
            }
        }
        pacc[0][t] = a0; pacc[1][t] = a1; pacc[2][t] = a2; pacc[3][t] = a3;
        __syncthreads();   // B1: pacc ready; all hs4 reads complete

        // ---- phases B+C: threads 0..255 (gates, h update, dense partials) ----
        float hnew[MB];
        if (t < NHID) {
            float4 ho = hs4[t];
            float hold[MB] = { ho.x, ho.y, ho.z, ho.w };
            {
#pragma clang fp contract(off)
#pragma unroll
                for (int m = 0; m < MB; ++m) {
                    const int sp = sPrev[m];
                    float xz = (sp == 0) ? kz0 : ((sp == 1) ? kz1 : 0.f);
                    float xr = (sp == 0) ? kr0 : ((sp == 1) ? kr1 : 0.f);
                    float xh = (sp == 0) ? kn0 : ((sp == 1) ? kn1 : 0.f);
                    xz = xz + b0z;  xr = xr + b0r;  xh = xh + b0n;
                    const float hz = pacc[m][t]       + b1z;
                    const float hr = pacc[m][t + 256] + b1r;
                    const float hn = pacc[m][t + 512] + b1n;
                    const float z = 1.0f / (1.0f + expf(-(xz + hz)));
                    const float r = 1.0f / (1.0f + expf(-(xr + hr)));
                    const float rhn = r * hn;
                    const float hh = tanhf(xh + rhn);
                    hnew[m] = z * hold[m] + (1.0f - z) * hh;
                }
            }
            hs4[t] = make_float4(hnew[0], hnew[1], hnew[2], hnew[3]);

            // dense logits partial reduction (h @ dense_w), waves 0..3
#pragma unroll
            for (int m = 0; m < MB; ++m) {
                float va = hnew[m] * dwa;
                float vb = hnew[m] * dwb;
#pragma unroll
                for (int off = 32; off > 0; off >>= 1) {
                    va += __shfl_xor(va, off, 64);
                    vb += __shfl_xor(vb, off, 64);
                }
                if (lane == 0) { wred[wv][2 * m] = va; wred[wv][2 * m + 1] = vb; }
            }
        }
        __syncthreads();   // B2: wred ready

        // ---- phase D: logits + gumbel + categorical + logP (4 threads) ----
        if (t < MB) {
            const int m = t;
            // same summation order as the verified kernel: w0+w1+w2+w3, then bias
            float l0 = wred[0][2 * m] + wred[1][2 * m] + wred[2][2 * m] + wred[3][2 * m];
            float l1 = wred[0][2 * m + 1] + wred[1][2 * m + 1] + wred[2][2 * m + 1] + wred[3][2 * m + 1];
            uint32_t o0a, o1a, o0b, o1b;
            const uint32_t fbase = 2u * (uint32_t)(b0 + m);
            threefry(keyA[n], keyB[n], 0u, fbase,      o0a, o1a);
            threefry(keyA[n], keyB[n], 0u, fbase + 1u, o0b, o1b);
            const float g0 = gumbel_from_bits(o0a ^ o1a);
            const float g1 = gumbel_from_bits(o0b ^ o1b);
            {
#pragma clang fp contract(off)
                l0 = l0 + dba;
                l1 = l1 + dbb;
                const float mx = fmaxf(l0, l1);
                const float e0 = expf(l0 - mx), e1 = expf(l1 - mx);
                const float den = e0 + e1;
                const float lp0 = logf(1e-10f + e0 / den);
                const float lp1 = logf(1e-10f + e1 / den);
                const float v0 = g0 + lp0;
                const float v1 = g1 + lp1;
                const int s = (v1 > v0) ? 1 : 0;   // argmax, first-index tie-break
                sPrev[m] = s;
                lgP[m] = lgP[m] + (s ? lp1 : lp0);
                out[(size_t)(b0 + m) * N_SITES + n] = (float)s;
            }
        }
        __syncthreads();   // B3: sPrev/hs4 stable for next step
    }

    if (t < MB) out[(size_t)NSAMP * N_SITES + (b0 + t)] = lgP[t];
}

extern "C" void kernel_launch(void* const* d_in, const int* in_sizes, int n_in,
                              void* d_out, int out_size, void* d_ws, size_t ws_size,
                              hipStream_t stream) {
    (void)in_sizes; (void)n_in; (void)d_ws; (void)ws_size; (void)out_size;
    const float* kern = (const float*)d_in[0];
    const float* rec  = (const float*)d_in[1];
    const float* bias = (const float*)d_in[2];
    const float* dwp  = (const float*)d_in[3];
    const float* dbp  = (const float*)d_in[4];
    float* out = (float*)d_out;
    rnn_sample_kernel<<<NSAMP / MB, TPB, 0, stream>>>(kern, rec, bias, dwp, dbp, out);
}